// Round 1
// baseline (1100.067 us; speedup 1.0000x reference)
//
#include <hip/hip_runtime.h>
#include <hip/hip_bf16.h>

// Nystromformer layer, MI355X. fp32 I/O, f16 MFMA internals, fp32 Newton-Schulz.
// R4: (a) pinv GEMMs K-split x4 -> 256 blocks (LDS-pipe-bound fix), atomic fp32
//     combine with beta folded into partials, E added by ks==0 slice;
//     (b) a3v GEMM split-K x8 via gemm_bt ATOMIC epilogue (was 8-block latency-bound);
//     (c) k_final decomposed: outh = a1@za3v^T (MFMA), conv in k_h, projection
//     + bias + x-residual as gemm_bt epilogue with f16 wout^T;
//     (d) k_scale fused into k_z0.

typedef _Float16 f16;
typedef f16 f16x2 __attribute__((ext_vector_type(2)));
typedef f16 f16x4 __attribute__((ext_vector_type(4)));
typedef f16 f16x8 __attribute__((ext_vector_type(8)));
typedef float f32x4 __attribute__((ext_vector_type(4)));

__device__ __forceinline__ float waveMax(float v){
  #pragma unroll
  for(int i=32;i>0;i>>=1) v = fmaxf(v, __shfl_xor(v, i));
  return v;
}
__device__ __forceinline__ float waveSum(float v){
  #pragma unroll
  for(int i=32;i>0;i>>=1) v += __shfl_xor(v, i);
  return v;
}
__device__ __forceinline__ float blockMaxF(float v, float* sm){
  v = waveMax(v);
  if((threadIdx.x&63)==0) sm[threadIdx.x>>6] = v;
  __syncthreads();
  v = fmaxf(fmaxf(sm[0],sm[1]), fmaxf(sm[2],sm[3]));
  __syncthreads();
  return v;
}
__device__ __forceinline__ float blockSumF(float v, float* sm){
  v = waveSum(v);
  if((threadIdx.x&63)==0) sm[threadIdx.x>>6] = v;
  __syncthreads();
  v = sm[0]+sm[1]+sm[2]+sm[3];
  __syncthreads();
  return v;
}

__device__ __forceinline__ void st_out(float* p, float v){ *p = v; }
__device__ __forceinline__ void st_out(f16* p, float v){ *p = (f16)v; }

__device__ __forceinline__ void async_cp16(const f16* g, const f16* l){
  __builtin_amdgcn_global_load_lds((const __attribute__((address_space(1))) void*)g,
                                   (__attribute__((address_space(3))) void*)l, 16, 0, 0);
}

// ---------------- LayerNorm: x fp32 [16384][512] -> xn f16 -------------------
__global__ __launch_bounds__(256) void k_ln(const float* __restrict__ x, const float* __restrict__ g,
                                            const float* __restrict__ be, f16* __restrict__ xn){
  __shared__ float sm[8];
  long row = blockIdx.x; int t = threadIdx.x;
  const float* xr = x + row*512;
  float v0 = xr[t], v1 = xr[t+256];
  float s = waveSum(v0+v1), ss = waveSum(v0*v0+v1*v1);
  if((t&63)==0){ sm[t>>6] = s; sm[(t>>6)+4] = ss; }
  __syncthreads();
  s = sm[0]+sm[1]+sm[2]+sm[3]; ss = sm[4]+sm[5]+sm[6]+sm[7];
  float mu = s*(1.f/512.f);
  float var = ss*(1.f/512.f) - mu*mu;
  float rstd = rsqrtf(var + 1e-5f);
  xn[row*512+t]     = (f16)((v0-mu)*rstd*g[t]     + be[t]);
  xn[row*512+t+256] = (f16)((v1-mu)*rstd*g[t+256] + be[t+256]);
}

// ------------- transpose w_qkv fp32 [512][192] -> wqkT f16 [256(pad)][512] ---
__global__ __launch_bounds__(256) void k_trw(const float* __restrict__ w, f16* __restrict__ wT){
  int i = blockIdx.x*256 + threadIdx.x;   // 131072
  int n = i>>9, k = i&511;
  wT[i] = (n<192) ? (f16)w[k*192+n] : (f16)0.0f;
}

// ------------- transpose w_out fp32 [64][512] -> woutT f16 [512][64] ---------
__global__ __launch_bounds__(256) void k_trW2(const float* __restrict__ w, f16* __restrict__ wT){
  int i = blockIdx.x*256 + threadIdx.x;   // 32768
  int n = i>>6, k = i&63;
  wT[i] = (f16)w[k*512+n];
}

// ---------------- shared MFMA GEMM: C[M][N] = A[M][K] * Bt[N][K]^T -----------
// 128x128 tile, BK=64, 4 waves (2x2 of 64x64), 16x16x32 f16 MFMA.
// kslog: split-K across 2^kslog z-slices (ATOMIC must be set). bias/resid: optional
// epilogue adds bias[col] and resid[row*N+col] (fp32).
template<typename OutT, bool ATOMIC=false>
__global__ __launch_bounds__(256) void gemm_bt(
    const f16* __restrict__ A, const f16* __restrict__ Bt, OutT* __restrict__ C,
    int M, int N, int K, long sA, long sB, long sC, int kbeg, int kend, int kslog,
    const float* __restrict__ bias, const float* __restrict__ resid)
{
  __shared__ f16 As[8192];
  __shared__ f16 Bs[8192];
  int zz = blockIdx.z;
  int b  = zz >> kslog;
  int ksl = zz & ((1<<kslog)-1);
  A  += (long)b * sA;  Bt += (long)b * sB;  C += (long)b * sC;
  int m0 = blockIdx.x*128, n0 = blockIdx.y*128;
  int t = threadIdx.x;
  int w = t>>6, lane = t&63;
  int quad = lane>>4, l16 = lane&15;
  int wr = w>>1, wc = w&1;
  int tiles = (kend - kbeg) >> 6;
  int per = tiles >> kslog;
  int kt0 = (kbeg>>6) + ksl*per;
  f32x4 acc[4][4] = {};
  for(int kt=kt0; kt<kt0+per; ++kt){
    #pragma unroll
    for(int i=0;i<4;++i){
      int G = (w<<8)+(i<<6)+lane;
      int row = G>>3, gs = G&7;
      int g = gs ^ (row&7);                       // XOR-swizzled granule
      int koff = (kt<<6)+(g<<3);
      const f16* ldst = As + (((w<<8)+(i<<6))<<3);  // wave-uniform base
      async_cp16(A + (long)(m0+row)*K + koff, ldst);
      const f16* ldst2 = Bs + (((w<<8)+(i<<6))<<3);
      async_cp16(Bt + (long)(n0+row)*K + koff, ldst2);
    }
    __syncthreads();
    #pragma unroll
    for(int kk=0; kk<2; ++kk){
      f16x8 af[4], bfr[4];
      int gb = (kk<<2) + quad;
      #pragma unroll
      for(int mi=0;mi<4;++mi){
        int row = (wr<<6)+(mi<<4)+l16;
        af[mi] = *(const f16x8*)(As + ((row<<6) + ((gb ^ (row&7))<<3)));
      }
      #pragma unroll
      for(int ni=0;ni<4;++ni){
        int row = (wc<<6)+(ni<<4)+l16;
        bfr[ni] = *(const f16x8*)(Bs + ((row<<6) + ((gb ^ (row&7))<<3)));
      }
      #pragma unroll
      for(int mi=0;mi<4;++mi){
        #pragma unroll
        for(int ni=0;ni<4;++ni)
          acc[mi][ni] = __builtin_amdgcn_mfma_f32_16x16x32_f16(af[mi], bfr[ni], acc[mi][ni], 0,0,0);
      }
    }
    __syncthreads();
  }
  #pragma unroll
  for(int mi=0;mi<4;++mi){
    int rowb = m0 + (wr<<6) + (mi<<4) + (quad<<2);
    #pragma unroll
    for(int ni=0;ni<4;++ni){
      int col = n0 + (wc<<6) + (ni<<4) + l16;
      if(col < N){
        #pragma unroll
        for(int r=0;r<4;++r){
          float v = acc[mi][ni][r];
          if(bias)  v += bias[col];
          if(resid) v += resid[(long)(rowb+r)*N + col];
          if constexpr(ATOMIC){
            atomicAdd((float*)(C + (long)(rowb+r)*N + col), v);
          } else {
            st_out(C + (long)(rowb+r)*N + col, v);
          }
        }
      }
    }
  }
}

// ---------------- split qkv fp32 [16384][192] -> qf16(*0.125), kf16, vf32 ----
__global__ __launch_bounds__(256) void k_split(const float* __restrict__ qkv,
    f16* __restrict__ qf, f16* __restrict__ kf, float* __restrict__ vf){
  int t = threadIdx.x;
  long row = (long)blockIdx.x*4 + (t>>6); int d = t&63;
  const float* p = qkv + row*192;
  qf[row*64+d] = (f16)(p[d]*0.125f);
  kf[row*64+d] = (f16)(p[d+64]);
  vf[row*64+d] = p[d+128];
}

// ---------------- v transpose: vf32 [b][4096][64] -> vT f16 [b][128pad][4096]
__global__ __launch_bounds__(256) void k_vT(const float* __restrict__ vf, f16* __restrict__ vT){
  __shared__ float tile[64][65];
  int b = blockIdx.y, n0 = blockIdx.x*64;
  int t = threadIdx.x; int c = t&63, r4 = t>>6;
  #pragma unroll
  for(int i=0;i<16;++i){ int r = i*4+r4; tile[r][c] = vf[((long)(b*4096 + n0 + r))*64 + c]; }
  __syncthreads();
  #pragma unroll
  for(int i=0;i<16;++i){ int d = i*4+r4;
    vT[((long)(b*128 + d))*4096 + n0 + c] = (f16)tile[c][d]; }
}

// ---------------- landmarks: mean over 16 consecutive rows -------------------
__global__ __launch_bounds__(256) void k_land(const f16* __restrict__ qf, const f16* __restrict__ kf,
                                              f16* __restrict__ ql, f16* __restrict__ kl){
  int t = threadIdx.x;
  int bm = blockIdx.x*4 + (t>>6); int d = t&63;   // bm in [0,1024)
  const f16* pq = qf + (long)bm*1024 + d;
  const f16* pk = kf + (long)bm*1024 + d;
  float sq=0.f, sk=0.f;
  #pragma unroll
  for(int i=0;i<16;++i){ sq += (float)pq[i*64]; sk += (float)pk[i*64]; }
  ql[bm*64+d] = (f16)(sq*0.0625f);
  kl[bm*64+d] = (f16)(sk*0.0625f);
}

// ---------------- softmax over 256 cols, wave per row, out f16 ---------------
__global__ __launch_bounds__(256) void k_softmax1(const float* __restrict__ s, f16* __restrict__ a){
  int t = threadIdx.x; int w = t>>6, lane = t&63;
  long row = (long)blockIdx.x*4 + w;
  float4 v = *(const float4*)(s + row*256 + lane*4);
  float m = waveMax(fmaxf(fmaxf(v.x,v.y),fmaxf(v.z,v.w)));
  float e0 = __expf(v.x-m), e1 = __expf(v.y-m), e2 = __expf(v.z-m), e3 = __expf(v.w-m);
  float inv = 1.f/waveSum(e0+e1+e2+e3);
  f16x4 o = {(f16)(e0*inv),(f16)(e1*inv),(f16)(e2*inv),(f16)(e3*inv)};
  *(f16x4*)(a + row*256 + lane*4) = o;
}

// ------- softmax2: a2 fp32 + column-sum atomics (rs) + rowsum max (csmax) ----
__global__ __launch_bounds__(256) void k_softmax2(const float* __restrict__ s, float* __restrict__ a2,
                                                  float* __restrict__ rs, unsigned* __restrict__ csmax){
  __shared__ float sm[4];
  int row = blockIdx.x; int t = threadIdx.x; int b = row>>8;
  float v = s[row*256+t];
  float m = blockMaxF(v, sm);
  float e = __expf(v-m);
  float sum = blockSumF(e, sm);
  float p = e/sum;
  a2[(long)row*256+t] = p;
  atomicAdd(&rs[b*256+t], p);
  float rowsum = blockSumF(p, sm);
  if(t==0) atomicMax(csmax, __float_as_uint(rowsum));
}

// ---------------- softmax over 4096 cols, block per row, out f16 -------------
__global__ __launch_bounds__(256) void k_softmax3(const float* __restrict__ s, f16* __restrict__ a){
  __shared__ float sm[4];
  long row = blockIdx.x; int t = threadIdx.x;
  const float* p = s + row*4096;
  float4 v[4]; float m = -1e30f;
  #pragma unroll
  for(int i=0;i<4;++i){
    v[i] = *(const float4*)(p + (i*256+t)*4);
    m = fmaxf(m, fmaxf(fmaxf(v[i].x,v[i].y),fmaxf(v[i].z,v[i].w)));
  }
  m = blockMaxF(m, sm);
  float sum = 0.f;
  #pragma unroll
  for(int i=0;i<4;++i){
    v[i].x = __expf(v[i].x-m); v[i].y = __expf(v[i].y-m);
    v[i].z = __expf(v[i].z-m); v[i].w = __expf(v[i].w-m);
    sum += v[i].x+v[i].y+v[i].z+v[i].w;
  }
  float inv = 1.f/blockSumF(sum, sm);
  f16* o = a + row*4096;
  #pragma unroll
  for(int i=0;i<4;++i){
    f16x4 ov = {(f16)(v[i].x*inv),(f16)(v[i].y*inv),(f16)(v[i].z*inv),(f16)(v[i].w*inv)};
    *(f16x4*)(o + (i*256+t)*4) = ov;
  }
}

// ---------------- z0 = a2^T * scale  (scale computed in-kernel) --------------
__global__ __launch_bounds__(256) void k_z0(const float* __restrict__ a2, const float* __restrict__ rs,
                                            const unsigned* __restrict__ csmax, float* __restrict__ z){
  __shared__ float tile[64][65];
  __shared__ float sm[4];
  int b = blockIdx.z; int i0 = blockIdx.x*64, j0 = blockIdx.y*64;
  int t = threadIdx.x;
  float m = fmaxf(fmaxf(rs[t],rs[t+256]), fmaxf(rs[t+512],rs[t+768]));
  m = blockMaxF(m, sm);
  float sc = 1.f/(__uint_as_float(*csmax)*m);
  const float* A = a2 + (long)b*65536; float* Z = z + (long)b*65536;
  int c = t&63, r4 = t>>6;
  #pragma unroll
  for(int i=0;i<16;++i){ int r = i*4+r4; tile[r][c] = A[(j0+r)*256 + i0 + c]; }
  __syncthreads();
  #pragma unroll
  for(int i=0;i<16;++i){ int r = i*4+r4; Z[(i0+r)*256 + j0 + c] = tile[c][r]*sc; }
}

// ------- fp32 batched GEMM partial, K-split x4: grid (Mt, Nt, 4batch*4ks) ----
// Each block computes beta*(A@B) over its K=64 slice and atomicAdds into D
// (pre-zeroed). ks==0 slice also adds alpha*E. LDS rows padded to 72 floats.
__global__ __launch_bounds__(256) void gemm256p(const float* __restrict__ A, const float* __restrict__ B,
    const float* __restrict__ E, float* __restrict__ D, int Ncols, float beta, float alpha){
  __shared__ float At[16][72];
  __shared__ float Bs[16][72];
  int z = blockIdx.z; int b = z&3, ks = z>>2;
  A += (long)b*65536;
  B += (long)b*256*Ncols;
  D += (long)b*256*Ncols;
  if(E) E += (long)b*256*Ncols;
  int r0 = blockIdx.x*64, c0 = blockIdx.y*64;
  int t = threadIdx.x, tr = t>>4, tc = t&15;
  int arow = t>>2, ac4 = t&3;
  int bk = t>>4, bn4 = t&15;
  float acc[4][4] = {};
  int kbase = ks*64;
  for(int k0=kbase;k0<kbase+64;k0+=16){
    float4 va = *(const float4*)(A + (long)(r0+arow)*256 + k0 + ac4*4);
    At[ac4*4+0][arow]=va.x; At[ac4*4+1][arow]=va.y; At[ac4*4+2][arow]=va.z; At[ac4*4+3][arow]=va.w;
    *(float4*)&Bs[bk][bn4*4] = *(const float4*)(B + (long)(k0+bk)*Ncols + c0 + bn4*4);
    __syncthreads();
    #pragma unroll
    for(int kk=0;kk<16;++kk){
      float4 a4 = *(const float4*)&At[kk][tr*4];
      float4 b4 = *(const float4*)&Bs[kk][tc*4];
      float av[4] = {a4.x,a4.y,a4.z,a4.w};
      float bv[4] = {b4.x,b4.y,b4.z,b4.w};
      #pragma unroll
      for(int i=0;i<4;++i){
        #pragma unroll
        for(int j=0;j<4;++j) acc[i][j] += av[i]*bv[j];
      }
    }
    __syncthreads();
  }
  #pragma unroll
  for(int i=0;i<4;++i){
    int row = r0 + tr*4 + i;
    #pragma unroll
    for(int j=0;j<4;++j){
      int col = c0 + tc*4 + j;
      float v = beta*acc[i][j];
      if(ks==0 && E) v += alpha*E[(long)row*Ncols+col];
      atomicAdd(&D[(long)row*Ncols+col], v);
    }
  }
}

// ---------------- z fp32 -> f16 ----------------------------------------------
__global__ __launch_bounds__(256) void k_zb(const float* __restrict__ z, f16* __restrict__ zb){
  int i = blockIdx.x*256 + threadIdx.x;
  zb[i] = (f16)z[i];
}

// ---------------- a3 f16 [b][256][4096] -> a3T f16 [b][4096][256] ------------
__global__ __launch_bounds__(256) void k_trA3(const f16* __restrict__ a3, f16* __restrict__ a3T){
  __shared__ f16 tile[64][74];
  int b = blockIdx.z; int n0 = blockIdx.x*64, m0 = blockIdx.y*64;
  const f16* A = a3 + (long)b*1048576; f16* T = a3T + (long)b*1048576;
  int t = threadIdx.x; int c = t&63, r4 = t>>6;
  #pragma unroll
  for(int i=0;i<16;++i){ int r = i*4+r4; tile[r][c] = A[(long)(m0+r)*4096 + n0 + c]; }
  __syncthreads();
  #pragma unroll
  for(int i=0;i<16;++i){ int nr = i*4+r4; T[(long)(n0+nr)*256 + m0 + c] = tile[c][nr]; }
}

// --------- za3v fp32 [4][256][64] -> zaT f16 [4][128pad][256] (transposed) ---
__global__ __launch_bounds__(256) void k_trZ(const float* __restrict__ za3v, f16* __restrict__ zaT){
  int i = blockIdx.x*256 + threadIdx.x;   // 131072
  int b = i>>15, j = i&32767; int d = j>>8, m = j&255;
  zaT[i] = (d<64) ? (f16)za3v[b*16384 + m*64 + d] : (f16)0.0f;
}

// --------- h = outh + depthwise conv(v), f16 out [16384][64] -----------------
__global__ __launch_bounds__(256) void k_h(const float* __restrict__ outh, const float* __restrict__ vf,
                                           const float* __restrict__ wconv, f16* __restrict__ h){
  __shared__ float wc[33];
  if(threadIdx.x<33) wc[threadIdx.x]=wconv[threadIdx.x];
  __syncthreads();
  long e = (long)blockIdx.x*256 + threadIdx.x;
  int d = (int)(e&63); long row = e>>6; int n = (int)(row&4095); long brow = row - n;
  float acc = outh[e];
  #pragma unroll
  for(int tau=0;tau<33;++tau){
    int nn = n + tau - 16;
    if(nn>=0 && nn<4096) acc += wc[tau]*vf[(brow+nn)*64 + d];
  }
  h[e] = (f16)acc;
}

extern "C" void kernel_launch(void* const* d_in, const int* in_sizes, int n_in,
                              void* d_out, int out_size, void* d_ws, size_t ws_size,
                              hipStream_t stream) {
  (void)in_sizes; (void)n_in; (void)out_size; (void)ws_size;
  const float* x     = (const float*)d_in[0];
  const float* gamma = (const float*)d_in[1];
  const float* beta  = (const float*)d_in[2];
  const float* wqkv  = (const float*)d_in[3];
  const float* wout  = (const float*)d_in[4];
  const float* bout  = (const float*)d_in[5];
  const float* wconv = (const float*)d_in[6];

  char* ws = (char*)d_ws;
  f16*   xn   = (f16*)(ws + 0);
  float* s3   = (float*)(ws + 0);          // reuse after qkv gemm
  float* s1   = (float*)(ws + 16777216);
  f16*   a3T  = (f16*)(ws + 16777216);     // reuse after softmax1
  f16*   U    = (f16*)(ws + 25165824);
  float* qkv  = (float*)(ws + 33554432);
  f16*   a3   = (f16*)(ws + 33554432);     // reuse after split
  f16*   a1   = (f16*)(ws + 46137344);
  f16*   qf   = (f16*)(ws + 54525952);
  f16*   kf   = (f16*)(ws + 56623104);
  float* vf   = (float*)(ws + 58720256);
  f16*   vT   = (f16*)(ws + 62914560);
  f16*   wqkT = (f16*)(ws + 67108864);
  f16*   ql   = (f16*)(ws + 67371008);
  f16*   kl   = (f16*)(ws + 67502080);
  float* s2   = (float*)(ws + 67633152);
  float* a2   = (float*)(ws + 68681728);
  float* zA   = (float*)(ws + 69730304);
  float* zB   = (float*)(ws + 70778880);
  float* xz   = (float*)(ws + 71827456);
  float* t1   = (float*)(ws + 72876032);
  float* t2   = (float*)(ws + 73924608);
  f16*   zb   = (f16*)(ws + 74973184);
  float* a3v  = (float*)(ws + 75497472);
  float* za3v = (float*)(ws + 75759616);
  float* rs   = (float*)(ws + 76021760);
  unsigned* csmax = (unsigned*)(ws + 76021760 + 4096);
  // new buffers (tail region)
  f16*   zaT  = (f16*)(ws + 76029952);     // [4][128][256] f16 = 262144 B
  f16*   woutT= (f16*)(ws + 76292096);     // [512][64] f16    = 65536 B
  float* outh = (float*)(ws + 76357632);   // [4][4096][64]    = 4194304 B
  f16*   h    = (f16*)(ws + 80551936);     // [16384][64] f16  = 2097152 B

  float* out0 = (float*)d_out;
  float* attn = out0 + 8388608;

  hipMemsetAsync(ws + 76021760, 0, 8192, stream);   // rs + csmax

  k_ln<<<16384,256,0,stream>>>(x, gamma, beta, xn);
  k_trw<<<512,256,0,stream>>>(wqkv, wqkT);
  k_trW2<<<128,256,0,stream>>>(wout, woutT);
  gemm_bt<float><<<dim3(128,2,1),256,0,stream>>>(xn, wqkT, qkv, 16384,192,512, 0L,0L,0L, 0,512,0, nullptr,nullptr);
  k_split<<<4096,256,0,stream>>>(qkv, qf, kf, vf);
  k_vT<<<dim3(64,4),256,0,stream>>>(vf, vT);
  k_land<<<256,256,0,stream>>>(qf, kf, ql, kl);
  // sims
  gemm_bt<float><<<dim3(32,2,4),256,0,stream>>>(qf, kl, s1, 4096,256,64, 262144L,16384L,1048576L, 0,64,0, nullptr,nullptr);
  gemm_bt<float><<<dim3(2,2,4),256,0,stream>>>(ql, kl, s2, 256,256,64, 16384L,16384L,65536L, 0,64,0, nullptr,nullptr);
  gemm_bt<float><<<dim3(2,32,4),256,0,stream>>>(ql, kf, s3, 256,4096,64, 16384L,262144L,1048576L, 0,64,0, nullptr,nullptr);
  k_softmax1<<<4096,256,0,stream>>>(s1, a1);
  k_softmax2<<<1024,256,0,stream>>>(s2, a2, rs, csmax);
  k_softmax3<<<1024,256,0,stream>>>(s3, a3);
  k_z0<<<dim3(4,4,4),256,0,stream>>>(a2, rs, csmax, zA);
  // Newton-Schulz pinv, 6 iterations, fp32, K-split x4 (grid 4,4,16 = 256 blocks)
  float* cur = zA; float* nxt = zB;
  for(int it=0; it<6; ++it){
    hipMemsetAsync(xz, 0, 1048576, stream);
    gemm256p<<<dim3(4,4,16),256,0,stream>>>(a2, cur, (const float*)nullptr, xz, 256, 1.f, 0.f);
    hipMemsetAsync(t1, 0, 1048576, stream);
    gemm256p<<<dim3(4,4,16),256,0,stream>>>(xz, xz, xz, t1, 256, -1.f, 7.f);
    hipMemsetAsync(t2, 0, 1048576, stream);
    gemm256p<<<dim3(4,4,16),256,0,stream>>>(xz, t1, xz, t2, 256, -1.f, 15.f);
    hipMemsetAsync(nxt, 0, 1048576, stream);
    gemm256p<<<dim3(4,4,16),256,0,stream>>>(cur, t2, cur, nxt, 256, -0.25f, 3.25f);
    float* tmp = cur; cur = nxt; nxt = tmp;
  }
  // cur == zA after 6 iterations
  k_zb<<<1024,256,0,stream>>>(cur, zb);
  k_trA3<<<dim3(64,4,4),256,0,stream>>>(a3, a3T);
  // a3v = a3 @ v : split-K x8 with atomic combine (was 8-block latency-bound)
  hipMemsetAsync(a3v, 0, 262144, stream);
  gemm_bt<float,true><<<dim3(2,1,32),256,0,stream>>>(a3, vT, a3v, 256,64,4096, 1048576L,524288L,16384L, 0,4096,3, nullptr,nullptr);
  // za3v = z @ a3v : K-split x4
  hipMemsetAsync(za3v, 0, 262144, stream);
  gemm256p<<<dim3(4,1,16),256,0,stream>>>(cur, a3v, (const float*)nullptr, za3v, 64, 1.f, 0.f);
  // outh = a1 @ za3v  (MFMA; Bt = za3v^T f16, zero-padded to 128 rows)
  k_trZ<<<512,256,0,stream>>>(za3v, zaT);
  gemm_bt<float><<<dim3(32,1,4),256,0,stream>>>(a1, zaT, outh, 4096,64,256, 1048576L,32768L,262144L, 0,256,0, nullptr,nullptr);
  // h = outh + conv(v), f16
  k_h<<<4096,256,0,stream>>>(outh, vf, wconv, h);
  // out0 = x + h @ wout^T + bout  (MFMA with bias+residual epilogue)
  gemm_bt<float><<<dim3(128,4,1),256,0,stream>>>(h, woutT, out0, 16384,512,64, 0L,0L,0L, 0,64,0, bout, x);
  // attn path
  gemm_bt<f16><<<dim3(32,2,4),256,0,stream>>>(a3T, zb, U, 4096,256,256, 1048576L,65536L,1048576L, 0,256,0, nullptr,nullptr);
  gemm_bt<float><<<dim3(32,32,4),256,0,stream>>>(a1, U, attn, 4096,4096,256, 1048576L,1048576L,16777216L, 0,256,0, nullptr,nullptr);
}

// Round 2
// 834.043 us; speedup vs baseline: 1.3190x; 1.3190x over previous
//
#include <hip/hip_runtime.h>
#include <hip/hip_bf16.h>

// Nystromformer layer, MI355X. fp32 I/O, f16 MFMA internals, fp32 Newton-Schulz.
// R5: launch-count diet + atomic-free split-K.
//  (a) pinv GEMMs: 256-block split-K x4, output = 4 PARTIAL slices (plain
//      stores); operand slices are summed during LDS staging of the NEXT
//      GEMM (L2-resident reads) -> no memsets, no atomics. 24 launches total.
//  (b) a3v: split-K x8 writes 8 partial slices; za3v GEMM sums them in staging.
//  (c) k_trw + k_trW2 + rs/csmax zeroing fused into k_prep.
//  Dispatches: 75 (R4) -> 47, zero hipMemsetAsync.

typedef _Float16 f16;
typedef f16 f16x2 __attribute__((ext_vector_type(2)));
typedef f16 f16x4 __attribute__((ext_vector_type(4)));
typedef f16 f16x8 __attribute__((ext_vector_type(8)));
typedef float f32x4 __attribute__((ext_vector_type(4)));

__device__ __forceinline__ float waveMax(float v){
  #pragma unroll
  for(int i=32;i>0;i>>=1) v = fmaxf(v, __shfl_xor(v, i));
  return v;
}
__device__ __forceinline__ float waveSum(float v){
  #pragma unroll
  for(int i=32;i>0;i>>=1) v += __shfl_xor(v, i);
  return v;
}
__device__ __forceinline__ float blockMaxF(float v, float* sm){
  v = waveMax(v);
  if((threadIdx.x&63)==0) sm[threadIdx.x>>6] = v;
  __syncthreads();
  v = fmaxf(fmaxf(sm[0],sm[1]), fmaxf(sm[2],sm[3]));
  __syncthreads();
  return v;
}
__device__ __forceinline__ float blockSumF(float v, float* sm){
  v = waveSum(v);
  if((threadIdx.x&63)==0) sm[threadIdx.x>>6] = v;
  __syncthreads();
  v = sm[0]+sm[1]+sm[2]+sm[3];
  __syncthreads();
  return v;
}

__device__ __forceinline__ void st_out(float* p, float v){ *p = v; }
__device__ __forceinline__ void st_out(f16* p, float v){ *p = (f16)v; }

__device__ __forceinline__ void async_cp16(const f16* g, const f16* l){
  __builtin_amdgcn_global_load_lds((const __attribute__((address_space(1))) void*)g,
                                   (__attribute__((address_space(3))) void*)l, 16, 0, 0);
}

// ---------------- LayerNorm: x fp32 [16384][512] -> xn f16 -------------------
__global__ __launch_bounds__(256) void k_ln(const float* __restrict__ x, const float* __restrict__ g,
                                            const float* __restrict__ be, f16* __restrict__ xn){
  __shared__ float sm[8];
  long row = blockIdx.x; int t = threadIdx.x;
  const float* xr = x + row*512;
  float v0 = xr[t], v1 = xr[t+256];
  float s = waveSum(v0+v1), ss = waveSum(v0*v0+v1*v1);
  if((t&63)==0){ sm[t>>6] = s; sm[(t>>6)+4] = ss; }
  __syncthreads();
  s = sm[0]+sm[1]+sm[2]+sm[3]; ss = sm[4]+sm[5]+sm[6]+sm[7];
  float mu = s*(1.f/512.f);
  float var = ss*(1.f/512.f) - mu*mu;
  float rstd = rsqrtf(var + 1e-5f);
  xn[row*512+t]     = (f16)((v0-mu)*rstd*g[t]     + be[t]);
  xn[row*512+t+256] = (f16)((v1-mu)*rstd*g[t+256] + be[t+256]);
}

// ---- prep: transpose w_qkv -> wqkT f16, w_out -> woutT f16, zero rs/csmax ---
__global__ __launch_bounds__(256) void k_prep(const float* __restrict__ wqkv, const float* __restrict__ wout,
    f16* __restrict__ wqkT, f16* __restrict__ woutT, float* __restrict__ rs, unsigned* __restrict__ csmax){
  int blk = blockIdx.x, t = threadIdx.x;
  if(blk < 512){
    int i = blk*256 + t; int n = i>>9, k = i&511;
    wqkT[i] = (n<192) ? (f16)wqkv[k*192+n] : (f16)0.0f;
  } else if(blk < 640){
    int i = (blk-512)*256 + t; int n = i>>6, k = i&63;
    woutT[i] = (f16)wout[k*512+n];
  } else {
    rs[t]=0.f; rs[t+256]=0.f; rs[t+512]=0.f; rs[t+768]=0.f;
    if(t==0) *csmax = 0u;
  }
}

// ---------------- shared MFMA GEMM: C[M][N] = A[M][K] * Bt[N][K]^T -----------
// 128x128 tile, BK=64, 4 waves (2x2 of 64x64), 16x16x32 f16 MFMA.
// kslog: split-K across 2^kslog z-slices; each slice STORES to C + ksl*sSlice
// (plain store, partial output). bias/resid: optional fp32 epilogue.
template<typename OutT>
__global__ __launch_bounds__(256) void gemm_bt(
    const f16* __restrict__ A, const f16* __restrict__ Bt, OutT* __restrict__ C,
    int M, int N, int K, long sA, long sB, long sC, int kbeg, int kend, int kslog,
    long sSlice, const float* __restrict__ bias, const float* __restrict__ resid)
{
  __shared__ f16 As[8192];
  __shared__ f16 Bs[8192];
  int zz = blockIdx.z;
  int b  = zz >> kslog;
  int ksl = zz & ((1<<kslog)-1);
  A  += (long)b * sA;  Bt += (long)b * sB;  C += (long)b * sC + (long)ksl * sSlice;
  int m0 = blockIdx.x*128, n0 = blockIdx.y*128;
  int t = threadIdx.x;
  int w = t>>6, lane = t&63;
  int quad = lane>>4, l16 = lane&15;
  int wr = w>>1, wc = w&1;
  int tiles = (kend - kbeg) >> 6;
  int per = tiles >> kslog;
  int kt0 = (kbeg>>6) + ksl*per;
  f32x4 acc[4][4] = {};
  for(int kt=kt0; kt<kt0+per; ++kt){
    #pragma unroll
    for(int i=0;i<4;++i){
      int G = (w<<8)+(i<<6)+lane;
      int row = G>>3, gs = G&7;
      int g = gs ^ (row&7);                       // XOR-swizzled granule
      int koff = (kt<<6)+(g<<3);
      const f16* ldst = As + (((w<<8)+(i<<6))<<3);  // wave-uniform base
      async_cp16(A + (long)(m0+row)*K + koff, ldst);
      const f16* ldst2 = Bs + (((w<<8)+(i<<6))<<3);
      async_cp16(Bt + (long)(n0+row)*K + koff, ldst2);
    }
    __syncthreads();
    #pragma unroll
    for(int kk=0; kk<2; ++kk){
      f16x8 af[4], bfr[4];
      int gb = (kk<<2) + quad;
      #pragma unroll
      for(int mi=0;mi<4;++mi){
        int row = (wr<<6)+(mi<<4)+l16;
        af[mi] = *(const f16x8*)(As + ((row<<6) + ((gb ^ (row&7))<<3)));
      }
      #pragma unroll
      for(int ni=0;ni<4;++ni){
        int row = (wc<<6)+(ni<<4)+l16;
        bfr[ni] = *(const f16x8*)(Bs + ((row<<6) + ((gb ^ (row&7))<<3)));
      }
      #pragma unroll
      for(int mi=0;mi<4;++mi){
        #pragma unroll
        for(int ni=0;ni<4;++ni)
          acc[mi][ni] = __builtin_amdgcn_mfma_f32_16x16x32_f16(af[mi], bfr[ni], acc[mi][ni], 0,0,0);
      }
    }
    __syncthreads();
  }
  #pragma unroll
  for(int mi=0;mi<4;++mi){
    int rowb = m0 + (wr<<6) + (mi<<4) + (quad<<2);
    #pragma unroll
    for(int ni=0;ni<4;++ni){
      int col = n0 + (wc<<6) + (ni<<4) + l16;
      if(col < N){
        #pragma unroll
        for(int r=0;r<4;++r){
          float v = acc[mi][ni][r];
          if(bias)  v += bias[col];
          if(resid) v += resid[(long)(rowb+r)*N + col];
          st_out(C + (long)(rowb+r)*N + col, v);
        }
      }
    }
  }
}

// ---------------- split qkv fp32 [16384][192] -> qf16(*0.125), kf16, vf32 ----
__global__ __launch_bounds__(256) void k_split(const float* __restrict__ qkv,
    f16* __restrict__ qf, f16* __restrict__ kf, float* __restrict__ vf){
  int t = threadIdx.x;
  long row = (long)blockIdx.x*4 + (t>>6); int d = t&63;
  const float* p = qkv + row*192;
  qf[row*64+d] = (f16)(p[d]*0.125f);
  kf[row*64+d] = (f16)(p[d+64]);
  vf[row*64+d] = p[d+128];
}

// ---------------- v transpose: vf32 [b][4096][64] -> vT f16 [b][128pad][4096]
__global__ __launch_bounds__(256) void k_vT(const float* __restrict__ vf, f16* __restrict__ vT){
  __shared__ float tile[64][65];
  int b = blockIdx.y, n0 = blockIdx.x*64;
  int t = threadIdx.x; int c = t&63, r4 = t>>6;
  #pragma unroll
  for(int i=0;i<16;++i){ int r = i*4+r4; tile[r][c] = vf[((long)(b*4096 + n0 + r))*64 + c]; }
  __syncthreads();
  #pragma unroll
  for(int i=0;i<16;++i){ int d = i*4+r4;
    vT[((long)(b*128 + d))*4096 + n0 + c] = (f16)tile[c][d]; }
}

// ---------------- landmarks: mean over 16 consecutive rows -------------------
__global__ __launch_bounds__(256) void k_land(const f16* __restrict__ qf, const f16* __restrict__ kf,
                                              f16* __restrict__ ql, f16* __restrict__ kl){
  int t = threadIdx.x;
  int bm = blockIdx.x*4 + (t>>6); int d = t&63;   // bm in [0,1024)
  const f16* pq = qf + (long)bm*1024 + d;
  const f16* pk = kf + (long)bm*1024 + d;
  float sq=0.f, sk=0.f;
  #pragma unroll
  for(int i=0;i<16;++i){ sq += (float)pq[i*64]; sk += (float)pk[i*64]; }
  ql[bm*64+d] = (f16)(sq*0.0625f);
  kl[bm*64+d] = (f16)(sk*0.0625f);
}

// ---------------- softmax over 256 cols, wave per row, out f16 ---------------
__global__ __launch_bounds__(256) void k_softmax1(const float* __restrict__ s, f16* __restrict__ a){
  int t = threadIdx.x; int w = t>>6, lane = t&63;
  long row = (long)blockIdx.x*4 + w;
  float4 v = *(const float4*)(s + row*256 + lane*4);
  float m = waveMax(fmaxf(fmaxf(v.x,v.y),fmaxf(v.z,v.w)));
  float e0 = __expf(v.x-m), e1 = __expf(v.y-m), e2 = __expf(v.z-m), e3 = __expf(v.w-m);
  float inv = 1.f/waveSum(e0+e1+e2+e3);
  f16x4 o = {(f16)(e0*inv),(f16)(e1*inv),(f16)(e2*inv),(f16)(e3*inv)};
  *(f16x4*)(a + row*256 + lane*4) = o;
}

// ------- softmax2: a2 fp32 + column-sum atomics (rs) + rowsum max (csmax) ----
__global__ __launch_bounds__(256) void k_softmax2(const float* __restrict__ s, float* __restrict__ a2,
                                                  float* __restrict__ rs, unsigned* __restrict__ csmax){
  __shared__ float sm[4];
  int row = blockIdx.x; int t = threadIdx.x; int b = row>>8;
  float v = s[row*256+t];
  float m = blockMaxF(v, sm);
  float e = __expf(v-m);
  float sum = blockSumF(e, sm);
  float p = e/sum;
  a2[(long)row*256+t] = p;
  atomicAdd(&rs[b*256+t], p);
  float rowsum = blockSumF(p, sm);
  if(t==0) atomicMax(csmax, __float_as_uint(rowsum));
}

// ---------------- softmax over 4096 cols, block per row, out f16 -------------
__global__ __launch_bounds__(256) void k_softmax3(const float* __restrict__ s, f16* __restrict__ a){
  __shared__ float sm[4];
  long row = blockIdx.x; int t = threadIdx.x;
  const float* p = s + row*4096;
  float4 v[4]; float m = -1e30f;
  #pragma unroll
  for(int i=0;i<4;++i){
    v[i] = *(const float4*)(p + (i*256+t)*4);
    m = fmaxf(m, fmaxf(fmaxf(v[i].x,v[i].y),fmaxf(v[i].z,v[i].w)));
  }
  m = blockMaxF(m, sm);
  float sum = 0.f;
  #pragma unroll
  for(int i=0;i<4;++i){
    v[i].x = __expf(v[i].x-m); v[i].y = __expf(v[i].y-m);
    v[i].z = __expf(v[i].z-m); v[i].w = __expf(v[i].w-m);
    sum += v[i].x+v[i].y+v[i].z+v[i].w;
  }
  float inv = 1.f/blockSumF(sum, sm);
  f16* o = a + row*4096;
  #pragma unroll
  for(int i=0;i<4;++i){
    f16x4 ov = {(f16)(v[i].x*inv),(f16)(v[i].y*inv),(f16)(v[i].z*inv),(f16)(v[i].w*inv)};
    *(f16x4*)(o + (i*256+t)*4) = ov;
  }
}

// ---------------- z0 = a2^T * scale  (scale computed in-kernel) --------------
__global__ __launch_bounds__(256) void k_z0(const float* __restrict__ a2, const float* __restrict__ rs,
                                            const unsigned* __restrict__ csmax, float* __restrict__ z){
  __shared__ float tile[64][65];
  __shared__ float sm[4];
  int b = blockIdx.z; int i0 = blockIdx.x*64, j0 = blockIdx.y*64;
  int t = threadIdx.x;
  float m = fmaxf(fmaxf(rs[t],rs[t+256]), fmaxf(rs[t+512],rs[t+768]));
  m = blockMaxF(m, sm);
  float sc = 1.f/(__uint_as_float(*csmax)*m);
  const float* A = a2 + (long)b*65536; float* Z = z + (long)b*65536;
  int c = t&63, r4 = t>>6;
  #pragma unroll
  for(int i=0;i<16;++i){ int r = i*4+r4; tile[r][c] = A[(j0+r)*256 + i0 + c]; }
  __syncthreads();
  #pragma unroll
  for(int i=0;i<16;++i){ int r = i*4+r4; Z[(i0+r)*256 + j0 + c] = tile[c][r]*sc; }
}

// ------- fp32 batched GEMM, split-K x4, partial-slice I/O --------------------
// grid (4, Ncols/64, 16): z -> b=z&3, ks=z>>2. Block computes beta*(A@B) over
// K-slice [ks*64, ks*64+64) and STORES to slice ks of D (no atomics).
// AS/BS/ES = slice counts of operands (1 = combined); slices are summed during
// staging (A/B) or epilogue (E, added by ks==0 only).
// A,E: [s][4][256][256] (slice stride 262144). B,D: [s][4][256][Ncols].
template<int AS, int BS, int ES>
__global__ __launch_bounds__(256) void gemm256s(const float* __restrict__ A, const float* __restrict__ B,
    const float* __restrict__ E, float* __restrict__ D, int Ncols, float beta, float alpha){
  __shared__ float At[16][72];
  __shared__ float Bs[16][72];
  int z = blockIdx.z; int b = z&3, ks = z>>2;
  long aOff = (long)b*65536;
  long bBatch = 256L*Ncols, bSl = 4L*bBatch;
  long bOff = (long)b*bBatch;
  long dOff = (long)ks*bSl + bOff;
  int r0 = blockIdx.x*64, c0 = blockIdx.y*64;
  int t = threadIdx.x, tr = t>>4, tc = t&15;
  int arow = t>>2, ac4 = t&3;
  int bk = t>>4, bn4 = t&15;
  float acc[4][4] = {};
  for(int k0=ks*64;k0<ks*64+64;k0+=16){
    const float* pa = A + aOff + (long)(r0+arow)*256 + k0 + ac4*4;
    float4 va = *(const float4*)pa;
    #pragma unroll
    for(int s=1;s<AS;++s){ float4 w = *(const float4*)(pa + (long)s*262144);
      va.x+=w.x; va.y+=w.y; va.z+=w.z; va.w+=w.w; }
    At[ac4*4+0][arow]=va.x; At[ac4*4+1][arow]=va.y; At[ac4*4+2][arow]=va.z; At[ac4*4+3][arow]=va.w;
    const float* pb = B + bOff + (long)(k0+bk)*Ncols + c0 + bn4*4;
    float4 vb = *(const float4*)pb;
    #pragma unroll
    for(int s=1;s<BS;++s){ float4 w = *(const float4*)(pb + (long)s*bSl);
      vb.x+=w.x; vb.y+=w.y; vb.z+=w.z; vb.w+=w.w; }
    *(float4*)&Bs[bk][bn4*4] = vb;
    __syncthreads();
    #pragma unroll
    for(int kk=0;kk<16;++kk){
      float4 a4 = *(const float4*)&At[kk][tr*4];
      float4 b4 = *(const float4*)&Bs[kk][tc*4];
      float av[4] = {a4.x,a4.y,a4.z,a4.w};
      float bv[4] = {b4.x,b4.y,b4.z,b4.w};
      #pragma unroll
      for(int i=0;i<4;++i){
        #pragma unroll
        for(int j=0;j<4;++j) acc[i][j] += av[i]*bv[j];
      }
    }
    __syncthreads();
  }
  #pragma unroll
  for(int i=0;i<4;++i){
    int row = r0 + tr*4 + i;
    #pragma unroll
    for(int j=0;j<4;++j){
      int col = c0 + tc*4 + j;
      float v = beta*acc[i][j];
      if(ES>0 && ks==0){
        const float* pe = E + aOff + (long)row*256 + col;
        float e = pe[0];
        #pragma unroll
        for(int s=1;s<ES;++s) e += pe[(long)s*262144];
        v += alpha*e;
      }
      D[dOff + (long)row*Ncols + col] = v;
    }
  }
}

// ---------------- z partials (4 slices) -> combined f16 ----------------------
__global__ __launch_bounds__(256) void k_zb(const float* __restrict__ z, f16* __restrict__ zb){
  int i = blockIdx.x*256 + threadIdx.x;
  float v = z[i] + z[i+262144] + z[i+524288] + z[i+786432];
  zb[i] = (f16)v;
}

// ---------------- a3 f16 [b][256][4096] -> a3T f16 [b][4096][256] ------------
__global__ __launch_bounds__(256) void k_trA3(const f16* __restrict__ a3, f16* __restrict__ a3T){
  __shared__ f16 tile[64][74];
  int b = blockIdx.z; int n0 = blockIdx.x*64, m0 = blockIdx.y*64;
  const f16* A = a3 + (long)b*1048576; f16* T = a3T + (long)b*1048576;
  int t = threadIdx.x; int c = t&63, r4 = t>>6;
  #pragma unroll
  for(int i=0;i<16;++i){ int r = i*4+r4; tile[r][c] = A[(long)(m0+r)*4096 + n0 + c]; }
  __syncthreads();
  #pragma unroll
  for(int i=0;i<16;++i){ int nr = i*4+r4; T[(long)(n0+nr)*256 + m0 + c] = tile[c][nr]; }
}

// ---- pW partials (4 slices of [4][256][64]) -> zaT f16 [4][128pad][256] -----
__global__ __launch_bounds__(256) void k_trZ(const float* __restrict__ pW, f16* __restrict__ zaT){
  int i = blockIdx.x*256 + threadIdx.x;   // 131072
  int b = i>>15, j = i&32767; int d = j>>8, m = j&255;
  float v = 0.f;
  if(d<64){
    long base = (long)b*16384 + (long)m*64 + d;
    v = pW[base] + pW[base+65536] + pW[base+131072] + pW[base+196608];
  }
  zaT[i] = (f16)v;
}

// --------- h = outh + depthwise conv(v), f16 out [16384][64] -----------------
__global__ __launch_bounds__(256) void k_h(const float* __restrict__ outh, const float* __restrict__ vf,
                                           const float* __restrict__ wconv, f16* __restrict__ h){
  __shared__ float wc[33];
  if(threadIdx.x<33) wc[threadIdx.x]=wconv[threadIdx.x];
  __syncthreads();
  long e = (long)blockIdx.x*256 + threadIdx.x;
  int d = (int)(e&63); long row = e>>6; int n = (int)(row&4095); long brow = row - n;
  float acc = outh[e];
  #pragma unroll
  for(int tau=0;tau<33;++tau){
    int nn = n + tau - 16;
    if(nn>=0 && nn<4096) acc += wc[tau]*vf[(brow+nn)*64 + d];
  }
  h[e] = (f16)acc;
}

extern "C" void kernel_launch(void* const* d_in, const int* in_sizes, int n_in,
                              void* d_out, int out_size, void* d_ws, size_t ws_size,
                              hipStream_t stream) {
  (void)in_sizes; (void)n_in; (void)out_size; (void)ws_size;
  const float* x     = (const float*)d_in[0];
  const float* gamma = (const float*)d_in[1];
  const float* beta  = (const float*)d_in[2];
  const float* wqkv  = (const float*)d_in[3];
  const float* wout  = (const float*)d_in[4];
  const float* bout  = (const float*)d_in[5];
  const float* wconv = (const float*)d_in[6];

  char* ws = (char*)d_ws;
  f16*   xn   = (f16*)(ws + 0);
  float* s3   = (float*)(ws + 0);          // reuse after qkv gemm
  float* s1   = (float*)(ws + 16777216);
  f16*   a3T  = (f16*)(ws + 16777216);     // reuse after softmax1
  f16*   U    = (f16*)(ws + 25165824);
  float* qkv  = (float*)(ws + 33554432);
  f16*   a3   = (f16*)(ws + 33554432);     // reuse after split
  f16*   a1   = (f16*)(ws + 46137344);
  f16*   qf   = (f16*)(ws + 54525952);
  f16*   kf   = (f16*)(ws + 56623104);
  float* vf   = (float*)(ws + 58720256);
  f16*   vT   = (f16*)(ws + 62914560);
  f16*   wqkT = (f16*)(ws + 67108864);
  f16*   ql   = (f16*)(ws + 67371008);
  f16*   kl   = (f16*)(ws + 67502080);
  float* s2   = (float*)(ws + 67633152);
  float* a2   = (float*)(ws + 68681728);
  float* zA   = (float*)(ws + 69730304);   // combined z0 [4][256][256]
  f16*   zb   = (f16*)(ws + 74973184);
  float* rs   = (float*)(ws + 76021760);
  unsigned* csmax = (unsigned*)(ws + 76021760 + 4096);
  f16*   zaT  = (f16*)(ws + 76029952);     // [4][128][256] f16
  f16*   woutT= (f16*)(ws + 76292096);     // [512][64] f16
  float* outh = (float*)(ws + 76357632);   // [4][4096][64] fp32
  f16*   h    = (f16*)(ws + 80551936);     // [16384][64] f16
  // partial-slice buffers (split-K x4 pinv chain), 4 MB each
  float* pXZ  = (float*)(ws + 82649088);
  float* pT1  = (float*)(ws + 86843392);
  float* pT2  = (float*)(ws + 91037696);
  float* pU0  = (float*)(ws + 95232000);
  float* pU1  = (float*)(ws + 99426304);
  float* a3vp = (float*)(ws + 103620608);  // [8][4][256][64] fp32 = 2 MB
  float* pW   = (float*)(ws + 105717760);  // [4][4][256][64] fp32 = 1 MB

  float* out0 = (float*)d_out;
  float* attn = out0 + 8388608;

  k_prep<<<641,256,0,stream>>>(wqkv, wout, wqkT, woutT, rs, csmax);
  k_ln<<<16384,256,0,stream>>>(x, gamma, beta, xn);
  gemm_bt<float><<<dim3(128,2,1),256,0,stream>>>(xn, wqkT, qkv, 16384,192,512, 0L,0L,0L, 0,512,0, 0L, nullptr,nullptr);
  k_split<<<4096,256,0,stream>>>(qkv, qf, kf, vf);
  k_vT<<<dim3(64,4),256,0,stream>>>(vf, vT);
  k_land<<<256,256,0,stream>>>(qf, kf, ql, kl);
  // sims
  gemm_bt<float><<<dim3(32,2,4),256,0,stream>>>(qf, kl, s1, 4096,256,64, 262144L,16384L,1048576L, 0,64,0, 0L, nullptr,nullptr);
  gemm_bt<float><<<dim3(2,2,4),256,0,stream>>>(ql, kl, s2, 256,256,64, 16384L,16384L,65536L, 0,64,0, 0L, nullptr,nullptr);
  gemm_bt<float><<<dim3(2,32,4),256,0,stream>>>(ql, kf, s3, 256,4096,64, 16384L,262144L,1048576L, 0,64,0, 0L, nullptr,nullptr);
  k_softmax1<<<4096,256,0,stream>>>(s1, a1);
  k_softmax2<<<1024,256,0,stream>>>(s2, a2, rs, csmax);
  k_softmax3<<<1024,256,0,stream>>>(s3, a3);
  k_z0<<<dim3(4,4,4),256,0,stream>>>(a2, rs, csmax, zA);
  // Newton-Schulz pinv, 6 iterations, fp32, split-K x4 partial slices
  {
    float* cur = zA;            // combined only for iteration 0
    float* bufs[2] = {pU0, pU1};
    for(int it=0; it<6; ++it){
      float* nxt = bufs[it&1];
      if(it==0) gemm256s<1,1,0><<<dim3(4,4,16),256,0,stream>>>(a2, cur, nullptr, pXZ, 256, 1.f, 0.f);
      else      gemm256s<1,4,0><<<dim3(4,4,16),256,0,stream>>>(a2, cur, nullptr, pXZ, 256, 1.f, 0.f);
      gemm256s<4,4,4><<<dim3(4,4,16),256,0,stream>>>(pXZ, pXZ, pXZ, pT1, 256, -1.f, 7.f);
      gemm256s<4,4,4><<<dim3(4,4,16),256,0,stream>>>(pXZ, pT1, pXZ, pT2, 256, -1.f, 15.f);
      if(it==0) gemm256s<1,4,1><<<dim3(4,4,16),256,0,stream>>>(cur, pT2, cur, nxt, 256, -0.25f, 3.25f);
      else      gemm256s<4,4,4><<<dim3(4,4,16),256,0,stream>>>(cur, pT2, cur, nxt, 256, -0.25f, 3.25f);
      cur = nxt;
    }
    // cur = final z, 4 partial slices
    k_zb<<<1024,256,0,stream>>>(cur, zb);
    k_trA3<<<dim3(64,4,4),256,0,stream>>>(a3, a3T);
    // a3v = a3 @ v : split-K x8, 8 partial slices (plain stores)
    gemm_bt<float><<<dim3(2,1,32),256,0,stream>>>(a3, vT, a3vp, 256,64,4096, 1048576L,524288L,16384L, 0,4096,3, 65536L, nullptr,nullptr);
    // za3v = z @ a3v : sums z's 4 slices (A) and a3v's 8 slices (B) in staging
    gemm256s<4,8,0><<<dim3(4,1,16),256,0,stream>>>(cur, a3vp, nullptr, pW, 64, 1.f, 0.f);
  }
  // combine pW slices -> zaT f16 (transposed, zero-padded to 128 rows)
  k_trZ<<<512,256,0,stream>>>(pW, zaT);
  // outh = a1 @ za3v^T (MFMA)
  gemm_bt<float><<<dim3(32,1,4),256,0,stream>>>(a1, zaT, outh, 4096,64,256, 1048576L,32768L,262144L, 0,256,0, 0L, nullptr,nullptr);
  // h = outh + conv(v), f16
  k_h<<<4096,256,0,stream>>>(outh, vf, wconv, h);
  // out0 = x + h @ wout^T + bout (MFMA with bias+residual epilogue)
  gemm_bt<float><<<dim3(128,4,1),256,0,stream>>>(h, woutT, out0, 16384,512,64, 0L,0L,0L, 0,64,0, 0L, bout, x);
  // attn path
  gemm_bt<f16><<<dim3(32,2,4),256,0,stream>>>(a3T, zb, U, 4096,256,256, 1048576L,65536L,1048576L, 0,256,0, 0L, nullptr,nullptr);
  gemm_bt<float><<<dim3(32,32,4),256,0,stream>>>(a1, U, attn, 4096,4096,256, 1048576L,1048576L,16777216L, 0,256,0, 0L, nullptr,nullptr);
}